// Round 1
// baseline (925.987 us; speedup 1.0000x reference)
//
#include <hip/hip_runtime.h>
#include <hip/hip_bf16.h>
#include <stdint.h>

#define BB 32
#define SS 2048
#define HH 1024
#define LL 32

typedef __attribute__((ext_vector_type(8))) __bf16 bf16x8;
typedef __attribute__((ext_vector_type(4))) float f32x4;

// ---------------------------------------------------------------------------
// Kernel 0: pack W (1024x32 f32, row-major) into bf16 MFMA B-fragment order:
// wt[k>>3][col][k&7]  (so a lane's 8 consecutive-K elements for one column are
// one contiguous 16B short8 load).
// ---------------------------------------------------------------------------
__global__ __launch_bounds__(256) void wt_pack(const float* __restrict__ W,
                                               __bf16* __restrict__ wt) {
    int idx = blockIdx.x * 256 + threadIdx.x;   // 0..32767 enumerating (k,j)
    int k = idx >> 5, j = idx & 31;
    wt[(((k >> 3) * 32 + j) << 3) + (k & 7)] = (__bf16)W[idx];
}

// ---------------------------------------------------------------------------
// Kernel 1: logits = hidden @ W + b via mfma_f32_16x16x32_bf16.
// Per wave: 16 rows x 32 cols, K-loop 32 iters (K=32 each, 2 N-tiles).
// A frag: row = lane&15, k = (lane>>4)*8 + e  (8 consecutive f32 -> bf16)
// B frag: col = lane&15 (+16), same k mapping -> one 16B load from wt.
// C frag: col = lane&15, row = (lane>>4)*4 + reg   [m89-verified layout]
// ---------------------------------------------------------------------------
__global__ __launch_bounds__(256) void gemm16(const float* __restrict__ hidden,
                                              const __bf16* __restrict__ wt,
                                              const float* __restrict__ bias,
                                              float* __restrict__ logits) {
    const int tid  = threadIdx.x;
    const int lane = tid & 63, wid = tid >> 6;
    const int r = lane & 15, g = lane >> 4;
    const long rowbase = ((long)blockIdx.x * 4 + wid) * 16;
    const float* arow = hidden + (rowbase + r) * HH;
    const bf16x8* wt8 = (const bf16x8*)wt;

    f32x4 acc0 = {0.f, 0.f, 0.f, 0.f};
    f32x4 acc1 = {0.f, 0.f, 0.f, 0.f};

#pragma unroll 2
    for (int kt = 0; kt < HH / 32; ++kt) {
        const int k0 = kt * 32 + g * 8;
        const f32x4 a0 = *(const f32x4*)(arow + k0);
        const f32x4 a1 = *(const f32x4*)(arow + k0 + 4);
        bf16x8 af;
        af[0] = (__bf16)a0[0]; af[1] = (__bf16)a0[1];
        af[2] = (__bf16)a0[2]; af[3] = (__bf16)a0[3];
        af[4] = (__bf16)a1[0]; af[5] = (__bf16)a1[1];
        af[6] = (__bf16)a1[2]; af[7] = (__bf16)a1[3];
        const int k4 = kt * 4 + g;
        bf16x8 b0 = wt8[k4 * 32 + r];
        bf16x8 b1 = wt8[k4 * 32 + r + 16];
        acc0 = __builtin_amdgcn_mfma_f32_16x16x32_bf16(af, b0, acc0, 0, 0, 0);
        acc1 = __builtin_amdgcn_mfma_f32_16x16x32_bf16(af, b1, acc1, 0, 0, 0);
    }

    const float bb0 = bias[r], bb1 = bias[r + 16];
#pragma unroll
    for (int q = 0; q < 4; ++q) {
        const long row = rowbase + g * 4 + q;
        logits[row * LL + r]      = acc0[q] + bb0;
        logits[row * LL + r + 16] = acc1[q] + bb1;
    }
}

// ---------------------------------------------------------------------------
// Kernel 2: per-batch CRF. Phase A (all 256 threads): mask-sum + numerator.
// Phase B (wave 0): serial forward scan. 64-lane split: j = tid&31 (label),
// h = tid>>5 selects which 16 of the i-sum this lane accumulates; combine via
// shfl_xor(32). alpha kept base-relative, re-based every 8 steps.
// ---------------------------------------------------------------------------
__global__ __launch_bounds__(256) void crf32(const float* __restrict__ logits,
                                             const float* __restrict__ trans,
                                             const float* __restrict__ startt,
                                             const float* __restrict__ endt,
                                             const int* __restrict__ labels,
                                             const int* __restrict__ mask,
                                             float* __restrict__ llh) {
    const int b = blockIdx.x, tid = threadIdx.x;
    const float* em = logits + (long)b * SS * LL;
    const int* lab = labels + b * SS;
    const int* mk  = mask + b * SS;

    __shared__ float s_red[4];
    __shared__ int   s_redi[4];
    __shared__ __align__(16) float s_p[64];

    // --- mask sum (for seq_end) ---
    int msum = 0;
    for (int t = tid; t < SS; t += 256) msum += (mk[t] != 0) ? 1 : 0;
#pragma unroll
    for (int m = 32; m >= 1; m >>= 1) msum += __shfl_xor(msum, m);
    if ((tid & 63) == 0) s_redi[tid >> 6] = msum;
    __syncthreads();
    const int seq_end = (s_redi[0] + s_redi[1] + s_redi[2] + s_redi[3]) - 1;

    // --- numerator ---
    float num = 0.f;
    for (int t = tid; t < SS; t += 256) {
        if (t == 0) {
            num += startt[lab[0]] + em[lab[0]];
        } else if (mk[t] != 0) {
            num += em[(long)t * LL + lab[t]] + trans[lab[t - 1] * LL + lab[t]];
        }
    }
    if (tid == 0) num += endt[lab[seq_end]];
#pragma unroll
    for (int m = 32; m >= 1; m >>= 1) num += __shfl_xor(num, m);
    if ((tid & 63) == 0) s_red[tid >> 6] = num;
    __syncthreads();
    if (tid >= 64) return;
    const float numer = s_red[0] + s_red[1] + s_red[2] + s_red[3];

    // --- forward scan (wave 0 only) ---
    const int j = tid & 31, h = tid >> 5;
    float E[16];
#pragma unroll
    for (int i = 0; i < 16; ++i) E[i] = __expf(trans[(h * 16 + i) * LL + j]);

    float alpha = startt[j] + em[j];   // base-relative alpha (lane j = label j)
    float btot = 0.f;
    // 2-deep emission/mask prefetch
    float em1 = em[LL + j];
    int   mk1 = mk[1];
    float em2 = em[2 * LL + j];
    int   mk2 = mk[2];

    for (int t = 1; t < SS; ++t) {
        if ((t & 7) == 1) {   // re-base every 8 steps: keeps exp() in range
            float mx = alpha;
#pragma unroll
            for (int m = 16; m >= 1; m >>= 1) mx = fmaxf(mx, __shfl_xor(mx, m));
            alpha -= mx;
            btot += mx;
        }
        const float emc = em1; const int mkc = mk1;
        em1 = em2; mk1 = mk2;
        const int tn = t + 2;
        if (tn < SS) { em2 = em[(long)tn * LL + j]; mk2 = mk[tn]; }

        const float p = __expf(alpha);
        s_p[tid] = p;
        asm volatile("s_waitcnt lgkmcnt(0)" ::: "memory");
        const f32x4* p4 = (const f32x4*)(s_p + h * 16);
        const f32x4 P0 = p4[0], P1 = p4[1], P2 = p4[2], P3 = p4[3];
        float c0 = fmaf(P0[3], E[3],  fmaf(P0[2], E[2],  fmaf(P0[1], E[1],  P0[0] * E[0])));
        float c1 = fmaf(P1[3], E[7],  fmaf(P1[2], E[6],  fmaf(P1[1], E[5],  P1[0] * E[4])));
        float c2 = fmaf(P2[3], E[11], fmaf(P2[2], E[10], fmaf(P2[1], E[9],  P2[0] * E[8])));
        float c3 = fmaf(P3[3], E[15], fmaf(P3[2], E[14], fmaf(P3[1], E[13], P3[0] * E[12])));
        float acch = (c0 + c1) + (c2 + c3);
        float accf = acch + __shfl_xor(acch, 32);   // combine the two i-halves
        float na = __logf(accf) + emc;
        alpha = mkc ? na : alpha;
    }

    // denominator = btot + logsumexp(alpha + end)
    float v = alpha + endt[j];
    float mx = v;
#pragma unroll
    for (int m = 16; m >= 1; m >>= 1) mx = fmaxf(mx, __shfl_xor(mx, m));
    float pe = __expf(v - mx);
#pragma unroll
    for (int m = 16; m >= 1; m >>= 1) pe += __shfl_xor(pe, m);
    if (tid == 0) llh[b] = numer - (btot + mx + __logf(pe));
}

// ---------------------------------------------------------------------------
// Kernel 3: loss = -mean(llh)
// ---------------------------------------------------------------------------
__global__ __launch_bounds__(64) void fin(const float* __restrict__ llh,
                                          float* __restrict__ out) {
    const int lane = threadIdx.x;
    float v = (lane < 32) ? llh[lane] : 0.f;
#pragma unroll
    for (int m = 16; m >= 1; m >>= 1) v += __shfl_xor(v, m);
    if (lane == 0) out[0] = -(v / 32.f);
}

extern "C" void kernel_launch(void* const* d_in, const int* in_sizes, int n_in,
                              void* d_out, int out_size, void* d_ws, size_t ws_size,
                              hipStream_t stream) {
    const float* hidden = (const float*)d_in[0];
    const float* W      = (const float*)d_in[1];
    const float* bias   = (const float*)d_in[2];
    const float* trans  = (const float*)d_in[3];
    const float* startt = (const float*)d_in[4];
    const float* endt   = (const float*)d_in[5];
    const int*   labels = (const int*)d_in[6];
    const int*   mask   = (const int*)d_in[7];

    float* out    = (float*)d_out;
    float* logits = out + 1;                       // d_out[0] = loss
    __bf16* wt    = (__bf16*)d_ws;                 // 64 KiB packed W
    float* llh    = (float*)((char*)d_ws + 65536); // 32 floats

    wt_pack<<<128, 256, 0, stream>>>(W, wt);
    gemm16<<<1024, 256, 0, stream>>>(hidden, wt, bias, logits);
    crf32<<<BB, 256, 0, stream>>>(logits, trans, startt, endt, labels, mask, llh);
    fin<<<1, 64, 0, stream>>>(llh, out);
}

// Round 2
// 435.906 us; speedup vs baseline: 2.1243x; 2.1243x over previous
//
#include <hip/hip_runtime.h>
#include <hip/hip_bf16.h>
#include <stdint.h>

#define BB 32
#define SS 2048
#define HH 1024
#define LL 32
#define NC 32     // chunks per sequence
#define CLEN 64   // steps per chunk

typedef __attribute__((ext_vector_type(8))) __bf16 bf16x8;
typedef __attribute__((ext_vector_type(4))) float f32x4;
typedef __attribute__((ext_vector_type(16))) float f32x16;

__device__ __forceinline__ uint32_t cvtpk(float lo, float hi) {
    uint32_t r;
    asm("v_cvt_pk_bf16_f32 %0, %1, %2" : "=v"(r) : "v"(lo), "v"(hi));
    return r;
}
__device__ __forceinline__ void pl32(uint32_t& a, uint32_t& b) {
    asm volatile("v_permlane32_swap_b32 %0, %1" : "+v"(a), "+v"(b));
}
__device__ __forceinline__ float qmax16(const f32x16& q) {
    float m0 = fmaxf(fmaxf(q[0], q[1]), fmaxf(q[2], q[3]));
    float m1 = fmaxf(fmaxf(q[4], q[5]), fmaxf(q[6], q[7]));
    float m2 = fmaxf(fmaxf(q[8], q[9]), fmaxf(q[10], q[11]));
    float m3 = fmaxf(fmaxf(q[12], q[13]), fmaxf(q[14], q[15]));
    float mx = fmaxf(fmaxf(m0, m1), fmaxf(m2, m3));
#pragma unroll
    for (int m = 32; m >= 1; m >>= 1) mx = fmaxf(mx, __shfl_xor(mx, m));
    return mx;
}

// ---------------------------------------------------------------------------
// Kernel 0: pack W into bf16 MFMA B-fragment order.
// ---------------------------------------------------------------------------
__global__ __launch_bounds__(256) void wt_pack(const float* __restrict__ W,
                                               __bf16* __restrict__ wt) {
    int idx = blockIdx.x * 256 + threadIdx.x;
    int k = idx >> 5, j = idx & 31;
    wt[(((k >> 3) * 32 + j) << 3) + (k & 7)] = (__bf16)W[idx];
}

// ---------------------------------------------------------------------------
// Kernel 1: logits = hidden @ W + b (MFMA 16x16x32 bf16) + exp(logits) epilogue.
// ---------------------------------------------------------------------------
__global__ __launch_bounds__(256) void gemm16(const float* __restrict__ hidden,
                                              const __bf16* __restrict__ wt,
                                              const float* __restrict__ bias,
                                              float* __restrict__ logits,
                                              float* __restrict__ expem) {
    const int tid  = threadIdx.x;
    const int lane = tid & 63, wid = tid >> 6;
    const int r = lane & 15, g = lane >> 4;
    const long rowbase = ((long)blockIdx.x * 4 + wid) * 16;
    const float* arow = hidden + (rowbase + r) * HH;
    const bf16x8* wt8 = (const bf16x8*)wt;

    f32x4 acc0 = {0.f, 0.f, 0.f, 0.f};
    f32x4 acc1 = {0.f, 0.f, 0.f, 0.f};

#pragma unroll 2
    for (int kt = 0; kt < HH / 32; ++kt) {
        const int k0 = kt * 32 + g * 8;
        const f32x4 a0 = *(const f32x4*)(arow + k0);
        const f32x4 a1 = *(const f32x4*)(arow + k0 + 4);
        bf16x8 af;
        af[0] = (__bf16)a0[0]; af[1] = (__bf16)a0[1];
        af[2] = (__bf16)a0[2]; af[3] = (__bf16)a0[3];
        af[4] = (__bf16)a1[0]; af[5] = (__bf16)a1[1];
        af[6] = (__bf16)a1[2]; af[7] = (__bf16)a1[3];
        const int k4 = kt * 4 + g;
        bf16x8 b0 = wt8[k4 * 32 + r];
        bf16x8 b1 = wt8[k4 * 32 + r + 16];
        acc0 = __builtin_amdgcn_mfma_f32_16x16x32_bf16(af, b0, acc0, 0, 0, 0);
        acc1 = __builtin_amdgcn_mfma_f32_16x16x32_bf16(af, b1, acc1, 0, 0, 0);
    }

    const float bb0 = bias[r], bb1 = bias[r + 16];
#pragma unroll
    for (int q = 0; q < 4; ++q) {
        const long row = rowbase + g * 4 + q;
        const float v0 = acc0[q] + bb0, v1 = acc1[q] + bb1;
        logits[row * LL + r]      = v0;
        logits[row * LL + r + 16] = v1;
        if (expem) {
            expem[row * LL + r]      = __expf(v0);
            expem[row * LL + r + 16] = __expf(v1);
        }
    }
}

// ---------------------------------------------------------------------------
// Kernel 2: per-(batch,chunk) composed transition matrix, exp-space MFMA scan.
// State = P[j][i] = exp(A_chunk^T - btot) as bf16 B-fragments (mfma 32x32x16).
// Also computes numerator/mask partials for its 64 timesteps.
// ---------------------------------------------------------------------------
template <int USE_EXPEM>
__global__ __launch_bounds__(64) void crf_chunk(
        const float* __restrict__ logits, const float* __restrict__ expem,
        const float* __restrict__ trans, const float* __restrict__ startt,
        const int* __restrict__ labels, const int* __restrict__ mask,
        uint4* __restrict__ afrag, float* __restrict__ btot_out,
        float* __restrict__ numpart, int* __restrict__ mkpart) {
    const int gc = blockIdx.x;
    const int b = gc >> 5, c = gc & 31;
    const int lane = threadIdx.x;
    const int col = lane & 31, h = lane >> 5;
    const float* em  = logits + (size_t)b * SS * LL;
    const float* eem = expem + (size_t)b * SS * LL;
    const int* lab = labels + b * SS;
    const int* mk  = mask + b * SS;

    // ---- numerator & mask partials ----
    {
        const int t = c * CLEN + lane;
        const int mt = (mk[t] != 0) ? 1 : 0;
        float np = 0.f;
        if (t == 0) np = startt[lab[0]] + em[lab[0]];
        else if (mt) np = em[t * LL + lab[t]] + trans[lab[t - 1] * LL + lab[t]];
        int ms = mt;
#pragma unroll
        for (int m = 32; m >= 1; m >>= 1) {
            np += __shfl_xor(np, m);
            ms += __shfl_xor(ms, m);
        }
        if (lane == 0) { numpart[gc] = np; mkpart[gc] = ms; }
    }

    // ---- constant A-fragments: EA[j][k] = exp(trans[k][j]), j=col, k=h*8+e ----
    bf16x8 EA1, EA2;
#pragma unroll
    for (int e = 0; e < 8; ++e) {
        EA1[e] = (__bf16)__expf(trans[(h * 8 + e) * LL + col]);
        EA2[e] = (__bf16)__expf(trans[(16 + h * 8 + e) * LL + col]);
    }

    // ---- identity state ----
    uint32_t b1[4], b2[4];
#pragma unroll
    for (int w = 0; w < 4; ++w) {
        const int k0 = h * 8 + 2 * w, k1 = k0 + 1;
        b1[w] = ((k0 == col) ? 0x3F80u : 0u) | (((k1 == col) ? 0x3F80u : 0u) << 16);
        b2[w] = (((16 + k0) == col) ? 0x3F80u : 0u) |
                ((((16 + k1) == col) ? 0x3F80u : 0u) << 16);
    }
    f32x16 cur;
#pragma unroll
    for (int qq = 0; qq < 16; ++qq) {
        const int j = (qq & 3) + 8 * (qq >> 2) + 4 * h;
        cur[qq] = (j == col) ? 1.f : 0.f;
    }

    float btot = 0.f;
    const int t0 = (c == 0) ? 1 : c * CLEN;
    const int t1 = c * CLEN + CLEN;

    // scale prefetch (2 deep): sX = exp(em[t][j]) per C-reg group
    f32x4 sA0, sA1, sA2, sA3, sB0, sB1, sB2, sB3;
    int mkA, mkB;
#define LOAD_SC(d0, d1, d2, d3, T)                                             \
    do {                                                                       \
        if (USE_EXPEM) {                                                       \
            const f32x4* p_ = (const f32x4*)(eem + (size_t)(T) * LL + 4 * h);  \
            d0 = p_[0]; d1 = p_[2]; d2 = p_[4]; d3 = p_[6];                    \
        } else {                                                               \
            const float* q_ = em + (size_t)(T) * LL + 4 * h;                   \
            _Pragma("unroll") for (int z_ = 0; z_ < 4; ++z_) {                 \
                d0[z_] = __expf(q_[z_]);                                       \
                d1[z_] = __expf(q_[8 + z_]);                                   \
                d2[z_] = __expf(q_[16 + z_]);                                  \
                d3[z_] = __expf(q_[24 + z_]);                                  \
            }                                                                  \
        }                                                                      \
    } while (0)

    LOAD_SC(sA0, sA1, sA2, sA3, t0);
    mkA = mk[t0];
    LOAD_SC(sB0, sB1, sB2, sB3, t0 + 1);
    mkB = mk[t0 + 1];

    for (int t = t0; t < t1; ++t) {
        const f32x4 c0 = sA0, c1 = sA1, c2 = sA2, c3 = sA3;
        const int mc = mkA;
        sA0 = sB0; sA1 = sB1; sA2 = sB2; sA3 = sB3; mkA = mkB;
        const int tp = (t + 2 < t1) ? t + 2 : t1 - 1;
        LOAD_SC(sB0, sB1, sB2, sB3, tp);
        mkB = mk[tp];

        if (mc) {
            f32x16 z;
#pragma unroll
            for (int qq = 0; qq < 16; ++qq) z[qq] = 0.f;
            f32x16 q = __builtin_amdgcn_mfma_f32_32x32x16_bf16(
                EA1, __builtin_bit_cast(bf16x8, *(const uint4*)b1), z, 0, 0, 0);
            q = __builtin_amdgcn_mfma_f32_32x32x16_bf16(
                EA2, __builtin_bit_cast(bf16x8, *(const uint4*)b2), q, 0, 0, 0);
            q[0] *= c0[0]; q[1] *= c0[1]; q[2] *= c0[2]; q[3] *= c0[3];
            q[4] *= c1[0]; q[5] *= c1[1]; q[6] *= c1[2]; q[7] *= c1[3];
            q[8] *= c2[0]; q[9] *= c2[1]; q[10] *= c2[2]; q[11] *= c2[3];
            q[12] *= c3[0]; q[13] *= c3[1]; q[14] *= c3[2]; q[15] *= c3[3];
            if ((t & 3) == 3) {
                const float mx = qmax16(q);
                const float inv = __builtin_amdgcn_rcpf(mx);
                btot += __logf(mx);
#pragma unroll
                for (int qq = 0; qq < 16; ++qq) q[qq] *= inv;
            }
            cur = q;
            uint32_t pA = cvtpk(q[0], q[1]),   pB = cvtpk(q[2], q[3]);
            uint32_t pC = cvtpk(q[4], q[5]),   pD = cvtpk(q[6], q[7]);
            uint32_t pE = cvtpk(q[8], q[9]),   pF = cvtpk(q[10], q[11]);
            uint32_t pG = cvtpk(q[12], q[13]), pH = cvtpk(q[14], q[15]);
            pl32(pA, pC); pl32(pB, pD); pl32(pE, pG); pl32(pF, pH);
            b1[0] = pA; b1[1] = pB; b1[2] = pC; b1[3] = pD;
            b2[0] = pE; b2[1] = pF; b2[2] = pG; b2[3] = pH;
        }
    }
#undef LOAD_SC

    // final normalize
    {
        const float mx = qmax16(cur);
        const float inv = __builtin_amdgcn_rcpf(mx);
        btot += __logf(mx);
#pragma unroll
        for (int qq = 0; qq < 16; ++qq) cur[qq] *= inv;
    }

    // transpose via LDS, store bf16 chunk matrix in cascade A-frag layout
    __shared__ float s_mat[32 * 36];
#pragma unroll
    for (int qq = 0; qq < 16; ++qq) {
        const int j = (qq & 3) + 8 * (qq >> 2) + 4 * h;
        s_mat[j * 36 + col] = cur[qq];
    }
    __syncthreads();
    const f32x4* sp = (const f32x4*)(s_mat + col * 36 + h * 16);
    const f32x4 r0 = sp[0], r1 = sp[1], r2 = sp[2], r3 = sp[3];
    uint4 p1, p2;
    p1.x = cvtpk(r0[0], r0[1]); p1.y = cvtpk(r0[2], r0[3]);
    p1.z = cvtpk(r1[0], r1[1]); p1.w = cvtpk(r1[2], r1[3]);
    p2.x = cvtpk(r2[0], r2[1]); p2.y = cvtpk(r2[2], r2[3]);
    p2.z = cvtpk(r3[0], r3[1]); p2.w = cvtpk(r3[2], r3[3]);
    uint4* afc = afrag + ((size_t)gc * 2 + h) * 64;
    afc[col] = p1;
    afc[32 + col] = p2;
    if (lane == 0) btot_out[gc] = btot;
}

// ---------------------------------------------------------------------------
// Kernel 3: per-batch cascade — multiply 32 chunk matrices, fold init/end,
// produce llh[b].
// ---------------------------------------------------------------------------
__global__ __launch_bounds__(64) void crf_cascade(
        const uint4* __restrict__ afrag, const float* __restrict__ btot_in,
        const float* __restrict__ numpart, const int* __restrict__ mkpart,
        const float* __restrict__ logits, const float* __restrict__ startt,
        const float* __restrict__ endt, const int* __restrict__ labels,
        float* __restrict__ llh) {
    const int b = blockIdx.x, lane = threadIdx.x;
    const int col = lane & 31, h = lane >> 5;

    uint32_t b1[4], b2[4];
#pragma unroll
    for (int w = 0; w < 4; ++w) {
        const int k0 = h * 8 + 2 * w, k1 = k0 + 1;
        b1[w] = ((k0 == col) ? 0x3F80u : 0u) | (((k1 == col) ? 0x3F80u : 0u) << 16);
        b2[w] = (((16 + k0) == col) ? 0x3F80u : 0u) |
                ((((16 + k1) == col) ? 0x3F80u : 0u) << 16);
    }
    f32x16 cur;
#pragma unroll
    for (int qq = 0; qq < 16; ++qq) {
        const int j = (qq & 3) + 8 * (qq >> 2) + 4 * h;
        cur[qq] = (j == col) ? 1.f : 0.f;
    }
    float btot = 0.f;

    uint4 a1n = afrag[((size_t)(b * NC) * 2 + 0) * 64 + lane];
    uint4 a2n = afrag[((size_t)(b * NC) * 2 + 1) * 64 + lane];

    for (int c = 0; c < NC; ++c) {
        const uint4 a1 = a1n, a2 = a2n;
        const int cn = (c + 1 < NC) ? c + 1 : c;
        a1n = afrag[((size_t)(b * NC + cn) * 2 + 0) * 64 + lane];
        a2n = afrag[((size_t)(b * NC + cn) * 2 + 1) * 64 + lane];

        f32x16 z;
#pragma unroll
        for (int qq = 0; qq < 16; ++qq) z[qq] = 0.f;
        f32x16 q = __builtin_amdgcn_mfma_f32_32x32x16_bf16(
            __builtin_bit_cast(bf16x8, a1),
            __builtin_bit_cast(bf16x8, *(const uint4*)b1), z, 0, 0, 0);
        q = __builtin_amdgcn_mfma_f32_32x32x16_bf16(
            __builtin_bit_cast(bf16x8, a2),
            __builtin_bit_cast(bf16x8, *(const uint4*)b2), q, 0, 0, 0);
        btot += btot_in[b * NC + c];
        if ((c & 1) == 1) {
            const float mx = qmax16(q);
            const float inv = __builtin_amdgcn_rcpf(mx);
            btot += __logf(mx);
#pragma unroll
            for (int qq = 0; qq < 16; ++qq) q[qq] *= inv;
        }
        cur = q;
        uint32_t pA = cvtpk(q[0], q[1]),   pB = cvtpk(q[2], q[3]);
        uint32_t pC = cvtpk(q[4], q[5]),   pD = cvtpk(q[6], q[7]);
        uint32_t pE = cvtpk(q[8], q[9]),   pF = cvtpk(q[10], q[11]);
        uint32_t pG = cvtpk(q[12], q[13]), pH = cvtpk(q[14], q[15]);
        pl32(pA, pC); pl32(pB, pD); pl32(pE, pG); pl32(pF, pH);
        b1[0] = pA; b1[1] = pB; b1[2] = pC; b1[3] = pD;
        b2[0] = pE; b2[1] = pF; b2[2] = pG; b2[3] = pH;
    }

    // denominator = btot + log( sum_{i,j} exp(init[i]) * P[j][i] * exp(end[j]) )
    float vs = 0.f;
#pragma unroll
    for (int qq = 0; qq < 16; ++qq) {
        const int j = (qq & 3) + 8 * (qq >> 2) + 4 * h;
        vs += cur[qq] * __expf(endt[j]);
    }
    vs *= __expf(startt[col] + logits[(size_t)b * SS * LL + col]);
#pragma unroll
    for (int m = 32; m >= 1; m >>= 1) vs += __shfl_xor(vs, m);
    const float denom = btot + __logf(vs);

    float np = (lane < NC) ? numpart[b * NC + lane] : 0.f;
    int ms = (lane < NC) ? mkpart[b * NC + lane] : 0;
#pragma unroll
    for (int m = 32; m >= 1; m >>= 1) {
        np += __shfl_xor(np, m);
        ms += __shfl_xor(ms, m);
    }
    if (lane == 0) {
        const int send = ms - 1;
        llh[b] = (np + endt[labels[b * SS + send]]) - denom;
    }
}

// ---------------------------------------------------------------------------
// Kernel 4: loss = -mean(llh)
// ---------------------------------------------------------------------------
__global__ __launch_bounds__(64) void fin(const float* __restrict__ llh,
                                          float* __restrict__ out) {
    const int lane = threadIdx.x;
    float v = (lane < 32) ? llh[lane] : 0.f;
#pragma unroll
    for (int m = 16; m >= 1; m >>= 1) v += __shfl_xor(v, m);
    if (lane == 0) out[0] = -(v / 32.f);
}

extern "C" void kernel_launch(void* const* d_in, const int* in_sizes, int n_in,
                              void* d_out, int out_size, void* d_ws, size_t ws_size,
                              hipStream_t stream) {
    const float* hidden = (const float*)d_in[0];
    const float* W      = (const float*)d_in[1];
    const float* bias   = (const float*)d_in[2];
    const float* trans  = (const float*)d_in[3];
    const float* startt = (const float*)d_in[4];
    const float* endt   = (const float*)d_in[5];
    const int*   labels = (const int*)d_in[6];
    const int*   mask   = (const int*)d_in[7];

    float* out    = (float*)d_out;
    float* logits = out + 1;

    char* ws = (char*)d_ws;
    __bf16* wt     = (__bf16*)ws;                        // 64 KiB
    float*  btot   = (float*)(ws + (64 << 10));          // 4 KiB
    float*  nump   = (float*)(ws + (68 << 10));          // 4 KiB
    int*    mkp    = (int*)(ws + (72 << 10));            // 4 KiB
    float*  llh    = (float*)(ws + (76 << 10));          // 128 B
    uint4*  afrag  = (uint4*)(ws + (128 << 10));         // 2 MiB
    const size_t off_expem = (128 << 10) + (size_t)BB * NC * 2 * 64 * 16;
    float* expem = (float*)(ws + off_expem);             // 8 MiB
    const size_t need = off_expem + (size_t)BB * SS * LL * 4;
    const int use_expem = (ws_size >= need);

    wt_pack<<<128, 256, 0, stream>>>(W, wt);
    gemm16<<<1024, 256, 0, stream>>>(hidden, wt, bias, logits,
                                     use_expem ? expem : nullptr);
    if (use_expem)
        crf_chunk<1><<<BB * NC, 64, 0, stream>>>(logits, expem, trans, startt,
                                                 labels, mask, afrag, btot, nump, mkp);
    else
        crf_chunk<0><<<BB * NC, 64, 0, stream>>>(logits, expem, trans, startt,
                                                 labels, mask, afrag, btot, nump, mkp);
    crf_cascade<<<BB, 64, 0, stream>>>(afrag, btot, nump, mkp, logits, startt,
                                       endt, labels, llh);
    fin<<<1, 64, 0, stream>>>(llh, out);
}